// Round 5
// baseline (149.745 us; speedup 1.0000x reference)
//
#include <hip/hip_runtime.h>
#include <math.h>

#define BB 1024
#define NN 256
#define VV 200
#define BT 16         // batch rows per k_final tile
#define NSH 16        // BN-stat atomic shards

// d_ws layout (floats):
//   [0    .. 256)        g_M   (245 used: up[98] | dn[98]@98 | pv[49]@196)
//   [256  .. 256+19200)  stats: g_sum[NSH][600] then g_ss[NSH][600]
//   [19456.. +614400)    g_x [3][1024][200]
#define WS_M    0
#define WS_STAT 256
#define WS_X    19456

// ---------------- K0: M = Wq @ Wk^T (blocks 0-2) + zero stats/out (all 8 blocks) ----------------
__global__ __launch_bounds__(256) void k_prep(const float* __restrict__ upWq, const float* __restrict__ upWk,
                                              const float* __restrict__ dnWq, const float* __restrict__ dnWk,
                                              const float* __restrict__ pvWq, const float* __restrict__ pvWk,
                                              float* __restrict__ ws, float* __restrict__ out) {
    __shared__ float wq[7 * VV];
    __shared__ float wk[14 * VV];
    int blk = blockIdx.x, tid = threadIdx.x;
    // zero stats shards + output, spread over all 8 blocks
    float* stat = ws + WS_STAT;
    for (int i = blk * 256 + tid; i < 2 * NSH * 600; i += 8 * 256) stat[i] = 0.f;
    for (int i = blk * 256 + tid; i < BB; i += 8 * 256) out[i] = 0.f;

    if (blk < 3) {
        const float* Wq = blk == 0 ? upWq : (blk == 1 ? dnWq : pvWq);
        const float* Wk = blk == 0 ? upWk : (blk == 1 ? dnWk : pvWk);
        int F = (blk == 2) ? 7 : 14;
        int off = blk == 0 ? 0 : (blk == 1 ? 98 : 196);
        for (int i = tid; i < 7 * VV; i += 256) wq[i] = Wq[i];
        for (int i = tid; i < F * VV; i += 256) wk[i] = Wk[i];
        __syncthreads();
        if (tid < 7 * F) {
            int i = tid / F, f = tid % F;
            float s = 0.f;
            for (int v = 0; v < VV; v++) s += wq[i * VV + v] * wk[f * VV + v];
            ws[WS_M + off + tid] = s;   // layout: [h] i*F + f
        }
    }
}

// ---------------- K1: attention — one wave per row, shuffle-only cross-lane ----------------
__global__ __launch_bounds__(256) void k_attn(
    const float* __restrict__ merged, const float* __restrict__ a,
    const float* __restrict__ upWv, const float* __restrict__ dnWv, const float* __restrict__ pvWv,
    float* __restrict__ ws) {
    int tid = threadIdx.x;
    int lane = tid & 63, wave = tid >> 6;
    int b = blockIdx.x * 4 + wave;

    __shared__ float sm[4 * NN * 15];   // 61440 B: 4 rows
    const float4* g4 = (const float4*)(merged + (size_t)blockIdx.x * 4 * NN * 15);
    float4* s4p = (float4*)sm;
    for (int i = tid; i < 4 * NN * 15 / 4; i += 256) s4p[i] = g4[i];
    __syncthreads();

    const float* row = sm + wave * NN * 15;
    const float* gM = ws + WS_M;
    float* g_sum = ws + WS_STAT;
    float* g_ss  = ws + WS_STAT + NSH * 600;
    float* g_x   = ws + WS_X;

    float ab = a[b];
    float subj_id = row[0];
    float subj_loc = row[2];
    float e1 = row[1], e2 = row[2], e3 = row[3], e4 = row[4], e5 = row[5], e6 = ab;

    float feat[4][14];
    float flag[4];
#pragma unroll
    for (int k = 0; k < 4; k++) {
        int base = (lane + 64 * k) * 15;
#pragma unroll
        for (int f = 0; f < 14; f++) feat[k][f] = row[base + f];
        flag[k] = row[base + 14];
        feat[k][0] -= subj_id;
        feat[k][7] -= subj_id;
    }
    if (lane == 0) feat[0][6] = ab;   // n==0 : merged[:,0,6]=a

    // eM[d] = sum_i ego[i] * M_h[i][f]
    float em = 0.f;
    if (lane < 35) {
        int h = lane < 14 ? 0 : (lane < 28 ? 1 : 2);
        int f = lane - (h == 0 ? 0 : (h == 1 ? 14 : 28));
        int F = (h == 2) ? 7 : 14;
        const float* M = gM + (h == 0 ? 0 : (h == 1 ? 98 : 196));
        em = e1 * M[1 * F + f] + e2 * M[2 * F + f] + e3 * M[3 * F + f] +
             e4 * M[4 * F + f] + e5 * M[5 * F + f] + e6 * M[6 * F + f];
    }

    float s0[4] = {0, 0, 0, 0}, s1[4] = {0, 0, 0, 0}, s2[4] = {0, 0, 0, 0};
#pragma unroll
    for (int f = 0; f < 14; f++) {
        float bv = __shfl(em, f);
#pragma unroll
        for (int k = 0; k < 4; k++) s0[k] += bv * feat[k][f];
    }
#pragma unroll
    for (int f = 0; f < 14; f++) {
        float bv = __shfl(em, 14 + f);
#pragma unroll
        for (int k = 0; k < 4; k++) s1[k] += bv * feat[k][f];
    }
#pragma unroll
    for (int f = 0; f < 7; f++) {
        float bv = __shfl(em, 28 + f);
#pragma unroll
        for (int k = 0; k < 4; k++) s2[k] += bv * feat[k][f];
    }

    const float scale = 7.0710678118654752e-2f;  // 1/sqrt(200)
#pragma unroll
    for (int k = 0; k < 4; k++) {
        float loc = feat[k][2];
        s0[k] = ((loc < subj_loc) && (flag[k] == 1.f)) ? s0[k] * scale : -1e9f;
        s1[k] = ((loc > subj_loc) && (flag[k] == 1.f)) ? s1[k] * scale : -1e9f;
        s2[k] = (flag[k] == 0.f) ? s2[k] * scale : -1e9f;
    }

    float m0 = fmaxf(fmaxf(s0[0], s0[1]), fmaxf(s0[2], s0[3]));
    float m1 = fmaxf(fmaxf(s1[0], s1[1]), fmaxf(s1[2], s1[3]));
    float m2 = fmaxf(fmaxf(s2[0], s2[1]), fmaxf(s2[2], s2[3]));
#pragma unroll
    for (int off = 32; off; off >>= 1) {
        m0 = fmaxf(m0, __shfl_xor(m0, off));
        m1 = fmaxf(m1, __shfl_xor(m1, off));
        m2 = fmaxf(m2, __shfl_xor(m2, off));
    }
    float p0[4], p1[4], p2[4];
    float z0 = 0.f, z1 = 0.f, z2 = 0.f;
#pragma unroll
    for (int k = 0; k < 4; k++) {
        p0[k] = expf(s0[k] - m0); z0 += p0[k];
        p1[k] = expf(s1[k] - m1); z1 += p1[k];
        p2[k] = expf(s2[k] - m2); z2 += p2[k];
    }
#pragma unroll
    for (int off = 32; off; off >>= 1) {
        z0 += __shfl_xor(z0, off);
        z1 += __shfl_xor(z1, off);
        z2 += __shfl_xor(z2, off);
    }
    float r0 = 1.f / z0, r1 = 1.f / z1, r2 = 1.f / z2;
#pragma unroll
    for (int k = 0; k < 4; k++) { p0[k] *= r0; p1[k] *= r1; p2[k] *= r2; }

    float pc[35];
#pragma unroll
    for (int f = 0; f < 14; f++) {
        float c0 = 0.f, c1 = 0.f;
#pragma unroll
        for (int k = 0; k < 4; k++) { c0 += p0[k] * feat[k][f]; c1 += p1[k] * feat[k][f]; }
        pc[f] = c0; pc[14 + f] = c1;
    }
#pragma unroll
    for (int f = 0; f < 7; f++) {
        float c2 = 0.f;
#pragma unroll
        for (int k = 0; k < 4; k++) c2 += p2[k] * feat[k][f];
        pc[28 + f] = c2;
    }
#pragma unroll
    for (int off = 32; off; off >>= 1)
#pragma unroll
        for (int j = 0; j < 35; j++) pc[j] += __shfl_xor(pc[j], off);

    int shard = blockIdx.x & (NSH - 1);
    const float* Wvs[3] = {upWv, dnWv, pvWv};
    float mh[3] = {m0, m1, m2};
    const int coff[3] = {0, 14, 28};
#pragma unroll
    for (int h = 0; h < 3; h++) {
        const float* Wv = Wvs[h];
        const float* c = pc + coff[h];
        int F = (h == 2) ? 7 : 14;
        bool empty = (mh[h] == -1e9f);
#pragma unroll
        for (int slot = 0; slot < 4; slot++) {
            int v = lane + 64 * slot;
            if (v < VV) {
                float val = 0.f;
                for (int f = 0; f < F; f++) val += c[f] * Wv[f * VV + v];
                if (empty) val = 0.f;
                g_x[((size_t)h * BB + b) * VV + v] = val;
                atomicAdd(&g_sum[shard * 600 + h * VV + v], val);
                atomicAdd(&g_ss[shard * 600 + h * VV + v], val * val);
            }
        }
    }
}

// ---------------- K2: BN finalize+apply + trunk GEMM / e-MLP, 4bb x 4w register tile ----------------
// grid = 64 tiles * 4 groups. BT=16 rows/tile. wave bg owns bb-quad 4*bg; lane wg(<50) owns w-quad 4*wg.
__global__ __launch_bounds__(256) void k_final(const float* __restrict__ merged, const float* __restrict__ a,
                                               const float* __restrict__ tW1, const float* __restrict__ tb1,
                                               const float* __restrict__ tW2, const float* __restrict__ tb2,
                                               const float* __restrict__ eW1, const float* __restrict__ eb1,
                                               const float* __restrict__ eW2, const float* __restrict__ eb2,
                                               const float* __restrict__ eW3, const float* __restrict__ eb3,
                                               const float* __restrict__ gamma, const float* __restrict__ beta,
                                               const float* __restrict__ ws,
                                               float* __restrict__ out) {
    int tile = blockIdx.x >> 2;
    int q = blockIdx.x & 3;
    int b0 = tile * BT;
    int tid = threadIdx.x;
    int lane = tid & 63, wave = tid >> 6;

    __shared__ __align__(16) float tsh[VV * BT];  // [v][bb]
    __shared__ float esh[BT][4];

    const float* g_sum = ws + WS_STAT;
    const float* g_ss  = ws + WS_STAT + NSH * 600;
    const float* g_x   = ws + WS_X;

    const float* W;   // 200x200 row-major [v][w]
    if (q < 3) {
        // BN finalize -> affine
        __shared__ float bnA[VV], bnB[VV];
        if (tid < VV) {
            float S = 0.f, S2 = 0.f;
#pragma unroll
            for (int s = 0; s < NSH; s++) {
                S += g_sum[s * 600 + q * VV + tid];
                S2 += g_ss[s * 600 + q * VV + tid];
            }
            float m = S * (1.f / BB);
            float var = S2 * (1.f / BB) - m * m;
            float rstd = rsqrtf(var + 1e-5f);
            float gv = gamma[tid];
            bnA[tid] = gv * rstd;
            bnB[tid] = beta[tid] - gv * rstd * m;
        }
        __syncthreads();
        for (int idx = tid; idx < BT * VV; idx += 256) {
            int v = idx % VV, bb = idx / VV;
            float val = g_x[((size_t)q * BB + b0 + bb) * VV + v];
            tsh[v * BT + bb] = bnA[v] * val + bnB[v];
        }
        W = tW1 + (size_t)q * VV * VV;
    } else {
        if (tid < BT) {
            const float* mrow = merged + (size_t)(b0 + tid) * NN * 15;
            esh[tid][0] = mrow[3];
            esh[tid][1] = mrow[4];
            esh[tid][2] = mrow[5];
            esh[tid][3] = a[b0 + tid];
        }
        __syncthreads();
        if (tid < VV) {
            float e0 = eW1[tid], e1 = eW1[VV + tid], e2 = eW1[2 * VV + tid], e3 = eW1[3 * VV + tid];
            float bias = eb1[tid];
#pragma unroll
            for (int bb = 0; bb < BT; bb++) {
                float qv = bias + esh[bb][0] * e0 + esh[bb][1] * e1 + esh[bb][2] * e2 + esh[bb][3] * e3;
                tsh[tid * BT + bb] = fmaxf(qv, 0.f);
            }
        }
        W = eW2;
    }
    __syncthreads();

    // ---- GEMM: acc[bb][j] for bb-quad (wave) x w-quad (lane) ----
    bool active = (lane < 50);
    int wbase = active ? lane * 4 : 0;
    int bbase = wave * 4;

    float4 bias4;
    if (q < 3) bias4 = *(const float4*)&tb1[q * VV + wbase];
    else       bias4 = *(const float4*)&eb2[wbase];

    float acc[4][4];
#pragma unroll
    for (int bb = 0; bb < 4; bb++) {
        acc[bb][0] = bias4.x; acc[bb][1] = bias4.y; acc[bb][2] = bias4.z; acc[bb][3] = bias4.w;
    }

    const float4* tq = (const float4*)&tsh[bbase];  // stride BT/4 float4 per v
#pragma unroll 8
    for (int v = 0; v < VV; v++) {
        float4 t4 = tq[v * (BT / 4)];
        float4 w4 = *(const float4*)&W[(size_t)v * VV + wbase];
        acc[0][0] += t4.x * w4.x; acc[0][1] += t4.x * w4.y; acc[0][2] += t4.x * w4.z; acc[0][3] += t4.x * w4.w;
        acc[1][0] += t4.y * w4.x; acc[1][1] += t4.y * w4.y; acc[1][2] += t4.y * w4.z; acc[1][3] += t4.y * w4.w;
        acc[2][0] += t4.z * w4.x; acc[2][1] += t4.z * w4.y; acc[2][2] += t4.z * w4.z; acc[2][3] += t4.z * w4.w;
        acc[3][0] += t4.w * w4.x; acc[3][1] += t4.w * w4.y; acc[3][2] += t4.w * w4.z; acc[3][3] += t4.w * w4.w;
    }

    // ---- epilogue ----
    float fin[4] = {0.f, 0.f, 0.f, 0.f};
    if (q < 3) {
        float4 w2 = *(const float4*)&tW2[q * VV + wbase];
#pragma unroll
        for (int bb = 0; bb < 4; bb++) {
            float h0 = acc[bb][0], h1 = acc[bb][1], h2 = acc[bb][2], h3 = acc[bb][3];
            h0 = h0 > 0.f ? h0 : expf(h0) - 1.f;
            h1 = h1 > 0.f ? h1 : expf(h1) - 1.f;
            h2 = h2 > 0.f ? h2 : expf(h2) - 1.f;
            h3 = h3 > 0.f ? h3 : expf(h3) - 1.f;
            fin[bb] = h0 * w2.x + h1 * w2.y + h2 * w2.z + h3 * w2.w;
        }
    } else {
        float4 w3 = *(const float4*)&eW3[wbase];
#pragma unroll
        for (int bb = 0; bb < 4; bb++) {
            fin[bb] = fmaxf(acc[bb][0], 0.f) * w3.x + fmaxf(acc[bb][1], 0.f) * w3.y +
                      fmaxf(acc[bb][2], 0.f) * w3.z + fmaxf(acc[bb][3], 0.f) * w3.w;
        }
    }
    if (!active) { fin[0] = fin[1] = fin[2] = fin[3] = 0.f; }

    // reduce across lanes (each wave owns distinct bb-quad; no cross-wave reduce needed)
#pragma unroll
    for (int off = 32; off; off >>= 1)
#pragma unroll
        for (int bb = 0; bb < 4; bb++) fin[bb] += __shfl_xor(fin[bb], off);

    if (lane == 0) {
        float cst = (q == 3) ? (eb3[0] + tb2[0] + tb2[1] + tb2[2]) : 0.f;
#pragma unroll
        for (int bb = 0; bb < 4; bb++) atomicAdd(&out[b0 + bbase + bb], fin[bb] + cst);
    }
}

extern "C" void kernel_launch(void* const* d_in, const int* in_sizes, int n_in,
                              void* d_out, int out_size, void* d_ws, size_t ws_size,
                              hipStream_t stream) {
    const float* merged = (const float*)d_in[0];
    const float* a      = (const float*)d_in[1];
    const float* upWq   = (const float*)d_in[2];
    const float* upWk   = (const float*)d_in[3];
    const float* upWv   = (const float*)d_in[4];
    const float* dnWq   = (const float*)d_in[5];
    const float* dnWk   = (const float*)d_in[6];
    const float* dnWv   = (const float*)d_in[7];
    const float* pvWq   = (const float*)d_in[8];
    const float* pvWk   = (const float*)d_in[9];
    const float* pvWv   = (const float*)d_in[10];
    const float* tW1    = (const float*)d_in[11];
    const float* tb1    = (const float*)d_in[12];
    const float* tW2    = (const float*)d_in[13];
    const float* tb2    = (const float*)d_in[14];
    const float* eW1    = (const float*)d_in[15];
    const float* eb1    = (const float*)d_in[16];
    const float* eW2    = (const float*)d_in[17];
    const float* eb2    = (const float*)d_in[18];
    const float* eW3    = (const float*)d_in[19];
    const float* eb3    = (const float*)d_in[20];
    const float* gamma  = (const float*)d_in[21];
    const float* beta   = (const float*)d_in[22];
    float* out = (float*)d_out;
    float* ws = (float*)d_ws;

    hipLaunchKernelGGL(k_prep, dim3(8), dim3(256), 0, stream, upWq, upWk, dnWq, dnWk, pvWq, pvWk, ws, out);
    hipLaunchKernelGGL(k_attn, dim3(BB / 4), dim3(256), 0, stream, merged, a, upWv, dnWv, pvWv, ws);
    hipLaunchKernelGGL(k_final, dim3((BB / BT) * 4), dim3(256), 0, stream, merged, a,
                       tW1, tb1, tW2, tb2, eW1, eb1, eW2, eb2, eW3, eb3, gamma, beta, ws, out);
}

// Round 6
// 139.968 us; speedup vs baseline: 1.0699x; 1.0699x over previous
//
#include <hip/hip_runtime.h>
#include <math.h>

#define BB 1024
#define NN 256
#define VV 200
#define BT 8          // batch rows per k_final tile
#define NSH 16        // BN-stat atomic shards

// d_ws layout (floats):
//   [0    .. 256)        g_M   (245 used: up[98] | dn[98]@98 | pv[49]@196)
//   [256  .. 256+19200)  stats: g_sum[NSH][600] then g_ss[NSH][600]
//   [19456.. +614400)    g_x [3][1024][200]
#define WS_M    0
#define WS_STAT 256
#define WS_X    19456

// ---------------- K0: M = Wq @ Wk^T (blocks 0-2) + zero stats/out (all 8 blocks) ----------------
__global__ __launch_bounds__(256) void k_prep(const float* __restrict__ upWq, const float* __restrict__ upWk,
                                              const float* __restrict__ dnWq, const float* __restrict__ dnWk,
                                              const float* __restrict__ pvWq, const float* __restrict__ pvWk,
                                              float* __restrict__ ws, float* __restrict__ out) {
    __shared__ float wq[7 * VV];
    __shared__ float wk[14 * VV];
    int blk = blockIdx.x, tid = threadIdx.x;
    float* stat = ws + WS_STAT;
    for (int i = blk * 256 + tid; i < 2 * NSH * 600; i += 8 * 256) stat[i] = 0.f;
    for (int i = blk * 256 + tid; i < BB; i += 8 * 256) out[i] = 0.f;

    if (blk < 3) {
        const float* Wq = blk == 0 ? upWq : (blk == 1 ? dnWq : pvWq);
        const float* Wk = blk == 0 ? upWk : (blk == 1 ? dnWk : pvWk);
        int F = (blk == 2) ? 7 : 14;
        int off = blk == 0 ? 0 : (blk == 1 ? 98 : 196);
        for (int i = tid; i < 7 * VV; i += 256) wq[i] = Wq[i];
        for (int i = tid; i < F * VV; i += 256) wk[i] = Wk[i];
        __syncthreads();
        if (tid < 7 * F) {
            int i = tid / F, f = tid % F;
            float s = 0.f;
            for (int v = 0; v < VV; v++) s += wq[i * VV + v] * wk[f * VV + v];
            ws[WS_M + off + tid] = s;   // layout: [h] i*F + f
        }
    }
}

// ---------------- K1: attention — ONE ROW PER BLOCK (grid 1024, 4 blocks/CU) ----------------
// thread n owns position n. LDS-transposed reductions instead of 64-wide shuffle butterflies.
__global__ __launch_bounds__(256) void k_attn(
    const float* __restrict__ merged, const float* __restrict__ a,
    const float* __restrict__ upWv, const float* __restrict__ dnWv, const float* __restrict__ pvWv,
    float* __restrict__ ws) {
    int b = blockIdx.x;
    int tid = threadIdx.x;         // == n
    int lane = tid & 63, wave = tid >> 6;

    __shared__ float sm[NN * 15];      // 15360 B, corrected in place
    __shared__ float eMsh[35];
    __shared__ float psh[3 * NN];      // softmax p per head
    __shared__ float part[245];        // 35 dots x 7 partials
    __shared__ float csh[35];
    __shared__ float wred[4][3];

    const float* gM = ws + WS_M;
    float* g_sum = ws + WS_STAT;
    float* g_ss  = ws + WS_STAT + NSH * 600;
    float* g_x   = ws + WS_X;

    // ---- stage row (coalesced float4) ----
    const float4* g4 = (const float4*)(merged + (size_t)b * NN * 15);
    float4* s4p = (float4*)sm;
    for (int i = tid; i < NN * 15 / 4; i += 256) s4p[i] = g4[i];
    __syncthreads();

    float ab = a[b];
    float subj_id = sm[0];
    float subj_loc = sm[2];
    __syncthreads();               // everyone read scalars before corrections

    // ---- corrections in LDS: f0 -= subj, f7 -= subj, [0][6] = a ----
    sm[tid * 15 + 0] -= subj_id;
    sm[tid * 15 + 7] -= subj_id;
    if (tid == 0) sm[6] = ab;
    // eM by threads 0..34 (sm[1..5] untouched by corrections)
    if (tid < 35) {
        int h = tid < 14 ? 0 : (tid < 28 ? 1 : 2);
        int f = tid - (h == 0 ? 0 : (h == 1 ? 14 : 28));
        int F = (h == 2) ? 7 : 14;
        const float* M = gM + (h == 0 ? 0 : (h == 1 ? 98 : 196));
        float e1 = sm[1], e2 = sm[2], e3 = sm[3], e4 = sm[4], e5 = sm[5];
        eMsh[tid] = e1 * M[1 * F + f] + e2 * M[2 * F + f] + e3 * M[3 * F + f] +
                    e4 * M[4 * F + f] + e5 * M[5 * F + f] + ab * M[6 * F + f];
    }
    __syncthreads();

    // ---- per-thread features + scores ----
    float feat[14];
#pragma unroll
    for (int f = 0; f < 14; f++) feat[f] = sm[tid * 15 + f];
    float flag = sm[tid * 15 + 14];
    float loc = feat[2];

    float s0 = 0.f, s1 = 0.f, s2 = 0.f;
#pragma unroll
    for (int f = 0; f < 14; f++) {
        s0 += eMsh[f] * feat[f];
        s1 += eMsh[14 + f] * feat[f];
    }
#pragma unroll
    for (int f = 0; f < 7; f++) s2 += eMsh[28 + f] * feat[f];

    const float scale = 7.0710678118654752e-2f;  // 1/sqrt(200)
    s0 = ((loc < subj_loc) && (flag == 1.f)) ? s0 * scale : -1e9f;
    s1 = ((loc > subj_loc) && (flag == 1.f)) ? s1 * scale : -1e9f;
    s2 = (flag == 0.f) ? s2 * scale : -1e9f;

    // ---- softmax: wave butterfly + 4-entry LDS combine ----
    float m0 = s0, m1 = s1, m2 = s2;
#pragma unroll
    for (int off = 32; off; off >>= 1) {
        m0 = fmaxf(m0, __shfl_xor(m0, off));
        m1 = fmaxf(m1, __shfl_xor(m1, off));
        m2 = fmaxf(m2, __shfl_xor(m2, off));
    }
    if (lane == 0) { wred[wave][0] = m0; wred[wave][1] = m1; wred[wave][2] = m2; }
    __syncthreads();
    m0 = fmaxf(fmaxf(wred[0][0], wred[1][0]), fmaxf(wred[2][0], wred[3][0]));
    m1 = fmaxf(fmaxf(wred[0][1], wred[1][1]), fmaxf(wred[2][1], wred[3][1]));
    m2 = fmaxf(fmaxf(wred[0][2], wred[1][2]), fmaxf(wred[2][2], wred[3][2]));
    float e0 = expf(s0 - m0), e1 = expf(s1 - m1), e2 = expf(s2 - m2);
    float z0 = e0, z1 = e1, z2 = e2;
#pragma unroll
    for (int off = 32; off; off >>= 1) {
        z0 += __shfl_xor(z0, off);
        z1 += __shfl_xor(z1, off);
        z2 += __shfl_xor(z2, off);
    }
    __syncthreads();  // wred reuse
    if (lane == 0) { wred[wave][0] = z0; wred[wave][1] = z1; wred[wave][2] = z2; }
    __syncthreads();
    z0 = wred[0][0] + wred[1][0] + wred[2][0] + wred[3][0];
    z1 = wred[0][1] + wred[1][1] + wred[2][1] + wred[3][1];
    z2 = wred[0][2] + wred[1][2] + wred[2][2] + wred[3][2];

    psh[0 * NN + tid] = e0 / z0;
    psh[1 * NN + tid] = e1 / z1;
    psh[2 * NN + tid] = e2 / z2;
    __syncthreads();

    // ---- c[h][f]: 35 dots x 7-thread partials over LDS ----
    if (tid < 245) {
        int d = tid / 7, j = tid % 7;
        int h = d < 14 ? 0 : (d < 28 ? 1 : 2);
        int f = d - (h == 0 ? 0 : (h == 1 ? 14 : 28));
        const float* p = psh + h * NN;
        float s = 0.f;
        for (int n = j; n < NN; n += 7) s += p[n] * sm[n * 15 + f];
        part[tid] = s;
    }
    __syncthreads();
    if (tid < 35) {
        float s = 0.f;
#pragma unroll
        for (int j = 0; j < 7; j++) s += part[tid * 7 + j];
        csh[tid] = s;
    }
    __syncthreads();

    // ---- projection: v = tid < 200, 3 heads, store + sharded stats ----
    if (tid < VV) {
        int shard = b & (NSH - 1);
        const float* Wvs[3] = {upWv, dnWv, pvWv};
        float mh[3] = {m0, m1, m2};
        const int coff[3] = {0, 14, 28};
        const int Fs[3] = {14, 14, 7};
#pragma unroll
        for (int h = 0; h < 3; h++) {
            const float* Wv = Wvs[h];
            const float* c = csh + coff[h];
            float val = 0.f;
            for (int f = 0; f < Fs[h]; f++) val += c[f] * Wv[f * VV + tid];
            if (mh[h] == -1e9f) val = 0.f;
            g_x[((size_t)h * BB + b) * VV + tid] = val;
            atomicAdd(&g_sum[shard * 600 + h * VV + tid], val);
            atomicAdd(&g_ss[shard * 600 + h * VV + tid], val * val);
        }
    }
}

// ---------------- K2: BN finalize+apply + trunk GEMM / e-MLP (R4 structure) ----------------
// grid = 128 tiles * 4 groups (BT=8 rows). q<3: trunk head q. q==3: e-MLP.
__global__ __launch_bounds__(256) void k_final(const float* __restrict__ merged, const float* __restrict__ a,
                                               const float* __restrict__ tW1, const float* __restrict__ tb1,
                                               const float* __restrict__ tW2, const float* __restrict__ tb2,
                                               const float* __restrict__ eW1, const float* __restrict__ eb1,
                                               const float* __restrict__ eW2, const float* __restrict__ eb2,
                                               const float* __restrict__ eW3, const float* __restrict__ eb3,
                                               const float* __restrict__ gamma, const float* __restrict__ beta,
                                               const float* __restrict__ ws,
                                               float* __restrict__ out) {
    int tile = blockIdx.x >> 2;
    int q = blockIdx.x & 3;
    int b0 = tile * BT;
    int tid = threadIdx.x;
    int lane = tid & 63, wave = tid >> 6;
    int w = tid;

    __shared__ __align__(16) float tT[VV * BT];  // [v][bb]
    __shared__ float redsh[4 * BT];
    __shared__ float esh[BT][4];

    const float* g_sum = ws + WS_STAT;
    const float* g_ss  = ws + WS_STAT + NSH * 600;
    const float* g_x   = ws + WS_X;

    float fin[BT];
#pragma unroll
    for (int bb = 0; bb < BT; bb++) fin[bb] = 0.f;

    if (q < 3) {
        __shared__ float bnA[VV], bnB[VV];
        if (w < VV) {
            float S = 0.f, S2 = 0.f;
#pragma unroll
            for (int s = 0; s < NSH; s++) {
                S += g_sum[s * 600 + q * VV + w];
                S2 += g_ss[s * 600 + q * VV + w];
            }
            float m = S * (1.f / BB);
            float var = S2 * (1.f / BB) - m * m;
            float rstd = rsqrtf(var + 1e-5f);
            float gv = gamma[w];
            bnA[w] = gv * rstd;
            bnB[w] = beta[w] - gv * rstd * m;
        }
        __syncthreads();
        for (int idx = tid; idx < BT * VV; idx += 256) {
            int v = idx % VV, bb = idx / VV;
            float val = g_x[((size_t)q * BB + b0 + bb) * VV + v];
            tT[v * BT + bb] = bnA[v] * val + bnB[v];
        }
        __syncthreads();

        if (w < VV) {
            float acc[BT];
            float bias = tb1[q * VV + w];
#pragma unroll
            for (int bb = 0; bb < BT; bb++) acc[bb] = bias;
            const float* W1 = tW1 + (size_t)q * VV * VV + w;
            const float4* tT4 = (const float4*)tT;
#pragma unroll 8
            for (int v = 0; v < VV; v++) {
                float w1 = W1[(size_t)v * VV];
                float4 t0 = tT4[v * 2 + 0];
                float4 t1 = tT4[v * 2 + 1];
                acc[0] += t0.x * w1; acc[1] += t0.y * w1; acc[2] += t0.z * w1; acc[3] += t0.w * w1;
                acc[4] += t1.x * w1; acc[5] += t1.y * w1; acc[6] += t1.z * w1; acc[7] += t1.w * w1;
            }
            float w2 = tW2[q * VV + w];
#pragma unroll
            for (int bb = 0; bb < BT; bb++) {
                float h = acc[bb];
                h = h > 0.f ? h : expf(h) - 1.f;   // ELU
                fin[bb] = h * w2;
            }
        }
    } else {
        if (tid < BT) {
            const float* mrow = merged + (size_t)(b0 + tid) * NN * 15;
            esh[tid][0] = mrow[3];
            esh[tid][1] = mrow[4];
            esh[tid][2] = mrow[5];
            esh[tid][3] = a[b0 + tid];
        }
        __syncthreads();
        if (w < VV) {
            float e0 = eW1[w], e1 = eW1[VV + w], e2 = eW1[2 * VV + w], e3 = eW1[3 * VV + w];
            float bias = eb1[w];
#pragma unroll
            for (int bb = 0; bb < BT; bb++) {
                float qv = bias + esh[bb][0] * e0 + esh[bb][1] * e1 + esh[bb][2] * e2 + esh[bb][3] * e3;
                tT[w * BT + bb] = fmaxf(qv, 0.f);
            }
        }
        __syncthreads();
        if (w < VV) {
            float acc[BT];
            float bias = eb2[w];
#pragma unroll
            for (int bb = 0; bb < BT; bb++) acc[bb] = bias;
            const float* W2 = eW2 + w;
            const float4* tT4 = (const float4*)tT;
#pragma unroll 8
            for (int v = 0; v < VV; v++) {
                float w2v = W2[(size_t)v * VV];
                float4 t0 = tT4[v * 2 + 0];
                float4 t1 = tT4[v * 2 + 1];
                acc[0] += t0.x * w2v; acc[1] += t0.y * w2v; acc[2] += t0.z * w2v; acc[3] += t0.w * w2v;
                acc[4] += t1.x * w2v; acc[5] += t1.y * w2v; acc[6] += t1.z * w2v; acc[7] += t1.w * w2v;
            }
            float w3 = eW3[w];
#pragma unroll
            for (int bb = 0; bb < BT; bb++) fin[bb] = fmaxf(acc[bb], 0.f) * w3;
        }
    }

#pragma unroll
    for (int bb = 0; bb < BT; bb++)
#pragma unroll
        for (int off = 32; off; off >>= 1) fin[bb] += __shfl_xor(fin[bb], off);
    if (lane == 0)
#pragma unroll
        for (int bb = 0; bb < BT; bb++) redsh[wave * BT + bb] = fin[bb];
    __syncthreads();
    if (tid < BT) {
        float tot = redsh[tid] + redsh[BT + tid] + redsh[2 * BT + tid] + redsh[3 * BT + tid];
        if (q == 3) tot += eb3[0] + tb2[0] + tb2[1] + tb2[2];
        atomicAdd(&out[b0 + tid], tot);
    }
}

extern "C" void kernel_launch(void* const* d_in, const int* in_sizes, int n_in,
                              void* d_out, int out_size, void* d_ws, size_t ws_size,
                              hipStream_t stream) {
    const float* merged = (const float*)d_in[0];
    const float* a      = (const float*)d_in[1];
    const float* upWq   = (const float*)d_in[2];
    const float* upWk   = (const float*)d_in[3];
    const float* upWv   = (const float*)d_in[4];
    const float* dnWq   = (const float*)d_in[5];
    const float* dnWk   = (const float*)d_in[6];
    const float* dnWv   = (const float*)d_in[7];
    const float* pvWq   = (const float*)d_in[8];
    const float* pvWk   = (const float*)d_in[9];
    const float* pvWv   = (const float*)d_in[10];
    const float* tW1    = (const float*)d_in[11];
    const float* tb1    = (const float*)d_in[12];
    const float* tW2    = (const float*)d_in[13];
    const float* tb2    = (const float*)d_in[14];
    const float* eW1    = (const float*)d_in[15];
    const float* eb1    = (const float*)d_in[16];
    const float* eW2    = (const float*)d_in[17];
    const float* eb2    = (const float*)d_in[18];
    const float* eW3    = (const float*)d_in[19];
    const float* eb3    = (const float*)d_in[20];
    const float* gamma  = (const float*)d_in[21];
    const float* beta   = (const float*)d_in[22];
    float* out = (float*)d_out;
    float* ws = (float*)d_ws;

    hipLaunchKernelGGL(k_prep, dim3(8), dim3(256), 0, stream, upWq, upWk, dnWq, dnWk, pvWq, pvWk, ws, out);
    hipLaunchKernelGGL(k_attn, dim3(BB), dim3(256), 0, stream, merged, a, upWv, dnWv, pvWv, ws);
    hipLaunchKernelGGL(k_final, dim3((BB / BT) * 4), dim3(256), 0, stream, merged, a,
                       tW1, tb1, tW2, tb2, eW1, eb1, eW2, eb2, eW3, eb3, gamma, beta, ws, out);
}

// Round 8
// 137.280 us; speedup vs baseline: 1.0908x; 1.0196x over previous
//
#include <hip/hip_runtime.h>
#include <math.h>

#define BB 1024
#define NN 256
#define VV 200
#define BT 8          // batch rows per k_final tile
#define NSH 16        // BN-stat atomic shards

// d_ws layout (floats):
//   [0    .. 256)        g_M   (245 used: up[98] | dn[98]@98 | pv[49]@196)
//   [256  .. 256+19200)  stats: g_sum[NSH][600] then g_ss[NSH][600]
//   [19456.. +614400)    g_x [3][1024][200]
#define WS_M    0
#define WS_STAT 256
#define WS_X    19456

// ---------------- K0: M = Wq @ Wk^T (blocks 0-2) + zero stats/out (all 8 blocks) ----------------
__global__ __launch_bounds__(256) void k_prep(const float* __restrict__ upWq, const float* __restrict__ upWk,
                                              const float* __restrict__ dnWq, const float* __restrict__ dnWk,
                                              const float* __restrict__ pvWq, const float* __restrict__ pvWk,
                                              float* __restrict__ ws, float* __restrict__ out) {
    __shared__ float wq[7 * VV];
    __shared__ float wk[14 * VV];
    int blk = blockIdx.x, tid = threadIdx.x;
    float* stat = ws + WS_STAT;
    for (int i = blk * 256 + tid; i < 2 * NSH * 600; i += 8 * 256) stat[i] = 0.f;
    for (int i = blk * 256 + tid; i < BB; i += 8 * 256) out[i] = 0.f;

    if (blk < 3) {
        const float* Wq = blk == 0 ? upWq : (blk == 1 ? dnWq : pvWq);
        const float* Wk = blk == 0 ? upWk : (blk == 1 ? dnWk : pvWk);
        int F = (blk == 2) ? 7 : 14;
        int off = blk == 0 ? 0 : (blk == 1 ? 98 : 196);
        for (int i = tid; i < 7 * VV; i += 256) wq[i] = Wq[i];
        for (int i = tid; i < F * VV; i += 256) wk[i] = Wk[i];
        __syncthreads();
        if (tid < 7 * F) {
            int i = tid / F, f = tid % F;
            float s = 0.f;
            for (int v = 0; v < VV; v++) s += wq[i * VV + v] * wk[f * VV + v];
            ws[WS_M + off + tid] = s;   // layout: [h] i*F + f
        }
    }
}

// ---------------- K1: attention — ONE ROW PER BLOCK (grid 1024, 4 blocks/CU) ----------------
// thread n owns position n. LDS-transposed reductions instead of 64-wide shuffle butterflies.
__global__ __launch_bounds__(256) void k_attn(
    const float* __restrict__ merged, const float* __restrict__ a,
    const float* __restrict__ upWv, const float* __restrict__ dnWv, const float* __restrict__ pvWv,
    float* __restrict__ ws) {
    int b = blockIdx.x;
    int tid = threadIdx.x;         // == n
    int lane = tid & 63, wave = tid >> 6;

    __shared__ float sm[NN * 15];      // 15360 B, corrected in place
    __shared__ float eMsh[35];
    __shared__ float psh[3 * NN];      // softmax p per head
    __shared__ float part[245];        // 35 dots x 7 partials
    __shared__ float csh[35];
    __shared__ float wred[4][3];

    const float* gM = ws + WS_M;
    float* g_sum = ws + WS_STAT;
    float* g_ss  = ws + WS_STAT + NSH * 600;
    float* g_x   = ws + WS_X;

    // ---- stage row (coalesced float4) ----
    const float4* g4 = (const float4*)(merged + (size_t)b * NN * 15);
    float4* s4p = (float4*)sm;
    for (int i = tid; i < NN * 15 / 4; i += 256) s4p[i] = g4[i];
    __syncthreads();

    float ab = a[b];
    float subj_id = sm[0];
    float subj_loc = sm[2];
    __syncthreads();               // everyone read scalars before corrections

    // ---- corrections in LDS: f0 -= subj, f7 -= subj, [0][6] = a ----
    sm[tid * 15 + 0] -= subj_id;
    sm[tid * 15 + 7] -= subj_id;
    if (tid == 0) sm[6] = ab;
    // eM by threads 0..34 (sm[1..5] untouched by corrections)
    if (tid < 35) {
        int h = tid < 14 ? 0 : (tid < 28 ? 1 : 2);
        int f = tid - (h == 0 ? 0 : (h == 1 ? 14 : 28));
        int F = (h == 2) ? 7 : 14;
        const float* M = gM + (h == 0 ? 0 : (h == 1 ? 98 : 196));
        float e1 = sm[1], e2 = sm[2], e3 = sm[3], e4 = sm[4], e5 = sm[5];
        eMsh[tid] = e1 * M[1 * F + f] + e2 * M[2 * F + f] + e3 * M[3 * F + f] +
                    e4 * M[4 * F + f] + e5 * M[5 * F + f] + ab * M[6 * F + f];
    }
    __syncthreads();

    // ---- per-thread features + scores ----
    float feat[14];
#pragma unroll
    for (int f = 0; f < 14; f++) feat[f] = sm[tid * 15 + f];
    float flag = sm[tid * 15 + 14];
    float loc = feat[2];

    float s0 = 0.f, s1 = 0.f, s2 = 0.f;
#pragma unroll
    for (int f = 0; f < 14; f++) {
        s0 += eMsh[f] * feat[f];
        s1 += eMsh[14 + f] * feat[f];
    }
#pragma unroll
    for (int f = 0; f < 7; f++) s2 += eMsh[28 + f] * feat[f];

    const float scale = 7.0710678118654752e-2f;  // 1/sqrt(200)
    s0 = ((loc < subj_loc) && (flag == 1.f)) ? s0 * scale : -1e9f;
    s1 = ((loc > subj_loc) && (flag == 1.f)) ? s1 * scale : -1e9f;
    s2 = (flag == 0.f) ? s2 * scale : -1e9f;

    // ---- softmax: wave butterfly + 4-entry LDS combine ----
    float m0 = s0, m1 = s1, m2 = s2;
#pragma unroll
    for (int off = 32; off; off >>= 1) {
        m0 = fmaxf(m0, __shfl_xor(m0, off));
        m1 = fmaxf(m1, __shfl_xor(m1, off));
        m2 = fmaxf(m2, __shfl_xor(m2, off));
    }
    if (lane == 0) { wred[wave][0] = m0; wred[wave][1] = m1; wred[wave][2] = m2; }
    __syncthreads();
    m0 = fmaxf(fmaxf(wred[0][0], wred[1][0]), fmaxf(wred[2][0], wred[3][0]));
    m1 = fmaxf(fmaxf(wred[0][1], wred[1][1]), fmaxf(wred[2][1], wred[3][1]));
    m2 = fmaxf(fmaxf(wred[0][2], wred[1][2]), fmaxf(wred[2][2], wred[3][2]));
    float e0 = expf(s0 - m0), e1 = expf(s1 - m1), e2 = expf(s2 - m2);
    float z0 = e0, z1 = e1, z2 = e2;
#pragma unroll
    for (int off = 32; off; off >>= 1) {
        z0 += __shfl_xor(z0, off);
        z1 += __shfl_xor(z1, off);
        z2 += __shfl_xor(z2, off);
    }
    __syncthreads();  // wred reuse
    if (lane == 0) { wred[wave][0] = z0; wred[wave][1] = z1; wred[wave][2] = z2; }
    __syncthreads();
    z0 = wred[0][0] + wred[1][0] + wred[2][0] + wred[3][0];
    z1 = wred[0][1] + wred[1][1] + wred[2][1] + wred[3][1];
    z2 = wred[0][2] + wred[1][2] + wred[2][2] + wred[3][2];

    psh[0 * NN + tid] = e0 / z0;
    psh[1 * NN + tid] = e1 / z1;
    psh[2 * NN + tid] = e2 / z2;
    __syncthreads();

    // ---- c[h][f]: 35 dots x 7-thread partials over LDS ----
    if (tid < 245) {
        int d = tid / 7, j = tid % 7;
        int h = d < 14 ? 0 : (d < 28 ? 1 : 2);
        int f = d - (h == 0 ? 0 : (h == 1 ? 14 : 28));
        const float* p = psh + h * NN;
        float s = 0.f;
        for (int n = j; n < NN; n += 7) s += p[n] * sm[n * 15 + f];
        part[tid] = s;
    }
    __syncthreads();
    if (tid < 35) {
        float s = 0.f;
#pragma unroll
        for (int j = 0; j < 7; j++) s += part[tid * 7 + j];
        csh[tid] = s;
    }
    __syncthreads();

    // ---- projection: v = tid < 200, 3 heads, store + sharded stats ----
    if (tid < VV) {
        int shard = b & (NSH - 1);
        const float* Wvs[3] = {upWv, dnWv, pvWv};
        float mh[3] = {m0, m1, m2};
        const int coff[3] = {0, 14, 28};
        const int Fs[3] = {14, 14, 7};
#pragma unroll
        for (int h = 0; h < 3; h++) {
            const float* Wv = Wvs[h];
            const float* c = csh + coff[h];
            float val = 0.f;
            for (int f = 0; f < Fs[h]; f++) val += c[f] * Wv[f * VV + tid];
            if (mh[h] == -1e9f) val = 0.f;
            g_x[((size_t)h * BB + b) * VV + tid] = val;
            atomicAdd(&g_sum[shard * 600 + h * VV + tid], val);
            atomicAdd(&g_ss[shard * 600 + h * VV + tid], val * val);
        }
    }
}

// ---------------- K2: BN finalize+apply + trunk GEMM / e-MLP (R4 structure) ----------------
// grid = 128 tiles * 4 groups (BT=8 rows). q<3: trunk head q. q==3: e-MLP.
__global__ __launch_bounds__(256) void k_final(const float* __restrict__ merged, const float* __restrict__ a,
                                               const float* __restrict__ tW1, const float* __restrict__ tb1,
                                               const float* __restrict__ tW2, const float* __restrict__ tb2,
                                               const float* __restrict__ eW1, const float* __restrict__ eb1,
                                               const float* __restrict__ eW2, const float* __restrict__ eb2,
                                               const float* __restrict__ eW3, const float* __restrict__ eb3,
                                               const float* __restrict__ gamma, const float* __restrict__ beta,
                                               const float* __restrict__ ws,
                                               float* __restrict__ out) {
    int tile = blockIdx.x >> 2;
    int q = blockIdx.x & 3;
    int b0 = tile * BT;
    int tid = threadIdx.x;
    int lane = tid & 63, wave = tid >> 6;
    int w = tid;

    __shared__ __align__(16) float tT[VV * BT];  // [v][bb]
    __shared__ float redsh[4 * BT];
    __shared__ float esh[BT][4];

    const float* g_sum = ws + WS_STAT;
    const float* g_ss  = ws + WS_STAT + NSH * 600;
    const float* g_x   = ws + WS_X;

    float fin[BT];
#pragma unroll
    for (int bb = 0; bb < BT; bb++) fin[bb] = 0.f;

    if (q < 3) {
        __shared__ float bnA[VV], bnB[VV];
        if (w < VV) {
            float S = 0.f, S2 = 0.f;
#pragma unroll
            for (int s = 0; s < NSH; s++) {
                S += g_sum[s * 600 + q * VV + w];
                S2 += g_ss[s * 600 + q * VV + w];
            }
            float m = S * (1.f / BB);
            float var = S2 * (1.f / BB) - m * m;
            float rstd = rsqrtf(var + 1e-5f);
            float gv = gamma[w];
            bnA[w] = gv * rstd;
            bnB[w] = beta[w] - gv * rstd * m;
        }
        __syncthreads();
        for (int idx = tid; idx < BT * VV; idx += 256) {
            int v = idx % VV, bb = idx / VV;
            float val = g_x[((size_t)q * BB + b0 + bb) * VV + v];
            tT[v * BT + bb] = bnA[v] * val + bnB[v];
        }
        __syncthreads();

        if (w < VV) {
            float acc[BT];
            float bias = tb1[q * VV + w];
#pragma unroll
            for (int bb = 0; bb < BT; bb++) acc[bb] = bias;
            const float* W1 = tW1 + (size_t)q * VV * VV + w;
            const float4* tT4 = (const float4*)tT;
#pragma unroll 8
            for (int v = 0; v < VV; v++) {
                float w1 = W1[(size_t)v * VV];
                float4 t0 = tT4[v * 2 + 0];
                float4 t1 = tT4[v * 2 + 1];
                acc[0] += t0.x * w1; acc[1] += t0.y * w1; acc[2] += t0.z * w1; acc[3] += t0.w * w1;
                acc[4] += t1.x * w1; acc[5] += t1.y * w1; acc[6] += t1.z * w1; acc[7] += t1.w * w1;
            }
            float w2 = tW2[q * VV + w];
#pragma unroll
            for (int bb = 0; bb < BT; bb++) {
                float h = acc[bb];
                h = h > 0.f ? h : expf(h) - 1.f;   // ELU
                fin[bb] = h * w2;
            }
        }
    } else {
        if (tid < BT) {
            const float* mrow = merged + (size_t)(b0 + tid) * NN * 15;
            esh[tid][0] = mrow[3];
            esh[tid][1] = mrow[4];
            esh[tid][2] = mrow[5];
            esh[tid][3] = a[b0 + tid];
        }
        __syncthreads();
        if (w < VV) {
            float e0 = eW1[w], e1 = eW1[VV + w], e2 = eW1[2 * VV + w], e3 = eW1[3 * VV + w];
            float bias = eb1[w];
#pragma unroll
            for (int bb = 0; bb < BT; bb++) {
                float qv = bias + esh[bb][0] * e0 + esh[bb][1] * e1 + esh[bb][2] * e2 + esh[bb][3] * e3;
                tT[w * BT + bb] = fmaxf(qv, 0.f);
            }
        }
        __syncthreads();
        if (w < VV) {
            float acc[BT];
            float bias = eb2[w];
#pragma unroll
            for (int bb = 0; bb < BT; bb++) acc[bb] = bias;
            const float* W2 = eW2 + w;
            const float4* tT4 = (const float4*)tT;
#pragma unroll 8
            for (int v = 0; v < VV; v++) {
                float w2v = W2[(size_t)v * VV];
                float4 t0 = tT4[v * 2 + 0];
                float4 t1 = tT4[v * 2 + 1];
                acc[0] += t0.x * w2v; acc[1] += t0.y * w2v; acc[2] += t0.z * w2v; acc[3] += t0.w * w2v;
                acc[4] += t1.x * w2v; acc[5] += t1.y * w2v; acc[6] += t1.z * w2v; acc[7] += t1.w * w2v;
            }
            float w3 = eW3[w];
#pragma unroll
            for (int bb = 0; bb < BT; bb++) fin[bb] = fmaxf(acc[bb], 0.f) * w3;
        }
    }

#pragma unroll
    for (int bb = 0; bb < BT; bb++)
#pragma unroll
        for (int off = 32; off; off >>= 1) fin[bb] += __shfl_xor(fin[bb], off);
    if (lane == 0)
#pragma unroll
        for (int bb = 0; bb < BT; bb++) redsh[wave * BT + bb] = fin[bb];
    __syncthreads();
    if (tid < BT) {
        float tot = redsh[tid] + redsh[BT + tid] + redsh[2 * BT + tid] + redsh[3 * BT + tid];
        if (q == 3) tot += eb3[0] + tb2[0] + tb2[1] + tb2[2];
        atomicAdd(&out[b0 + tid], tot);
    }
}

extern "C" void kernel_launch(void* const* d_in, const int* in_sizes, int n_in,
                              void* d_out, int out_size, void* d_ws, size_t ws_size,
                              hipStream_t stream) {
    const float* merged = (const float*)d_in[0];
    const float* a      = (const float*)d_in[1];
    const float* upWq   = (const float*)d_in[2];
    const float* upWk   = (const float*)d_in[3];
    const float* upWv   = (const float*)d_in[4];
    const float* dnWq   = (const float*)d_in[5];
    const float* dnWk   = (const float*)d_in[6];
    const float* dnWv   = (const float*)d_in[7];
    const float* pvWq   = (const float*)d_in[8];
    const float* pvWk   = (const float*)d_in[9];
    const float* pvWv   = (const float*)d_in[10];
    const float* tW1    = (const float*)d_in[11];
    const float* tb1    = (const float*)d_in[12];
    const float* tW2    = (const float*)d_in[13];
    const float* tb2    = (const float*)d_in[14];
    const float* eW1    = (const float*)d_in[15];
    const float* eb1    = (const float*)d_in[16];
    const float* eW2    = (const float*)d_in[17];
    const float* eb2    = (const float*)d_in[18];
    const float* eW3    = (const float*)d_in[19];
    const float* eb3    = (const float*)d_in[20];
    const float* gamma  = (const float*)d_in[21];
    const float* beta   = (const float*)d_in[22];
    float* out = (float*)d_out;
    float* ws = (float*)d_ws;

    hipLaunchKernelGGL(k_prep, dim3(8), dim3(256), 0, stream, upWq, upWk, dnWq, dnWk, pvWq, pvWk, ws, out);
    hipLaunchKernelGGL(k_attn, dim3(BB), dim3(256), 0, stream, merged, a, upWv, dnWv, pvWv, ws);
    hipLaunchKernelGGL(k_final, dim3((BB / BT) * 4), dim3(256), 0, stream, merged, a,
                       tW1, tb1, tW2, tb2, eW1, eb1, eW2, eb2, eW3, eb3, gamma, beta, ws, out);
}